// Round 2
// baseline (284.514 us; speedup 1.0000x reference)
//
#include <hip/hip_runtime.h>
#include <hip/hip_fp16.h>

typedef __attribute__((ext_vector_type(8))) short short8;

#define BB 8
#define CC 7
#define HH 512
#define WW 512
#define HW (HH*WW)
#define NBLK (16*16*8)

// ws layout:
//   [0,224)    28 doubles: [0]=focal [1]=bce [2..8]=sumP [9..15]=inter [16..22]=cnt [23..27]=topo_num
//   [224,228)  uint ticket counter
//   [256, 256+2MB)       hmask (bmask OR'ed horizontally +-2)
//   [256+2MB, 256+4MB)   rmask (hmask OR'ed vertically +-2) = final region>0 bits
//   bmask itself lives only in LDS (fused kernel).

__device__ __forceinline__ unsigned bmask_at(const int* __restrict__ tg, int y, int x) {
    // boundary bit c = |lap(onehot_c)|>0, zero-padded 3x3 laplacian [0,1,0;1,-4,1;0,1,0]
    int idx = y * WW + x;
    int t = tg[idx];
    unsigned orm = 0; int nfirst = -1; int same = 1; int ninb = 0;
    if (y > 0)      { int tn = tg[idx - WW]; orm |= 1u << tn; if (nfirst < 0) nfirst = tn; else same &= (tn == nfirst); ninb++; }
    if (y < HH - 1) { int tn = tg[idx + WW]; orm |= 1u << tn; if (nfirst < 0) nfirst = tn; else same &= (tn == nfirst); ninb++; }
    if (x > 0)      { int tn = tg[idx - 1];  orm |= 1u << tn; if (nfirst < 0) nfirst = tn; else same &= (tn == nfirst); ninb++; }
    if (x < WW - 1) { int tn = tg[idx + 1];  orm |= 1u << tn; if (nfirst < 0) nfirst = tn; else same &= (tn == nfirst); ninb++; }
    unsigned andm = (ninb == 4 && same) ? (1u << nfirst) : 0u;
    unsigned cbit = 1u << t;
    return (orm & ~cbit) | (cbit & ~andm);
}

// ---------------------------------------------------------------------------
// Pass 1: bmask + horizontal 5-OR fused. One block = one image row.
__global__ __launch_bounds__(256) void bmaskh_kernel(const int* __restrict__ tgt,
                                                     unsigned char* __restrict__ hmask) {
    __shared__ unsigned char sm[516];
    int row = blockIdx.x & (HH - 1);
    int b = blockIdx.x >> 9;
    const int* tg = tgt + (size_t)b * HW;
    for (int x = threadIdx.x; x < 516; x += 256) {
        int xx = x - 2;
        unsigned bits = 0;
        if ((unsigned)xx < WW) bits = bmask_at(tg, row, xx);
        sm[x] = (unsigned char)bits;
    }
    __syncthreads();
    size_t base = (size_t)b * HW + (size_t)row * WW;
    for (int x = threadIdx.x; x < WW; x += 256) {
        unsigned m = sm[x] | sm[x + 1] | sm[x + 2] | sm[x + 3] | sm[x + 4];
        hmask[base + x] = (unsigned char)m;
    }
}

// ---------------------------------------------------------------------------
// Pass 2: vertical 5-OR, dword-vectorized (4 pixels/thread).
__global__ __launch_bounds__(256) void vor_kernel(const unsigned char* __restrict__ hmask,
                                                  unsigned char* __restrict__ rmask) {
    int g = blockIdx.x * 256 + threadIdx.x;      // dword index, total BB*HW/4
    if (g >= BB * HW / 4) return;
    int b = g >> 16;                              // HW/4 = 65536 dwords per image
    int rem = g & 65535;
    int y = rem >> 7;                             // 128 dwords per row
    int x4 = rem & 127;
    const unsigned* src = (const unsigned*)(hmask + (size_t)b * HW);
    unsigned m = 0;
#pragma unroll
    for (int dy = -2; dy <= 2; dy++) {
        int yy = y + dy;
        if ((unsigned)yy < HH) m |= src[yy * 128 + x4];
    }
    ((unsigned*)(rmask + (size_t)b * HW))[y * 128 + x4] = m;
}

// ---------------------------------------------------------------------------
// Pass 3: fused main. 32x32 outputs/block; 34x34 halo softmax in LDS as f16.
__global__ __launch_bounds__(256) void main_kernel(const float* __restrict__ logits,
                                                   const int* __restrict__ tgt,
                                                   const float* __restrict__ cw,
                                                   const unsigned char* __restrict__ rmask,
                                                   double* __restrict__ acc,
                                                   unsigned* __restrict__ ticket,
                                                   float* __restrict__ out) {
    __shared__ unsigned short sp[1156 * 8];  // f16 probs, 8 slots/pixel (7 used), 18.5 KB
    __shared__ unsigned char st[1160];       // target class per halo pixel (255 = OOB)
    __shared__ float sw[8];
    __shared__ float sred[4 * 28];

    const int tid = threadIdx.x;
    const int b = blockIdx.z;
    const int x0 = blockIdx.x * 32 - 1;
    const int y0 = blockIdx.y * 32 - 1;
    if (tid < 7) sw[tid] = cw[tid];

    const float* lg = logits + (size_t)b * CC * HW;
    const int* tg = tgt + (size_t)b * HW;

    // ---- Phase A: softmax for halo tile -> packed f16 LDS ----
    for (int p = tid; p < 1156; p += 256) {
        int iy = p / 34;
        int ix = p - iy * 34;
        int y = y0 + iy, x = x0 + ix;
        short8 w = (short8)0;
        int tv = 255;
        if ((unsigned)x < WW && (unsigned)y < HH) {
            const float* lp = lg + y * WW + x;
            float l[7];
#pragma unroll
            for (int c = 0; c < 7; c++) l[c] = lp[c * HW];
            float m = l[0];
#pragma unroll
            for (int c = 1; c < 7; c++) m = fmaxf(m, l[c]);
            float e[7]; float se = 0.f;
#pragma unroll
            for (int c = 0; c < 7; c++) { e[c] = __expf(l[c] - m); se += e[c]; }
            float inv = 1.0f / se;
#pragma unroll
            for (int c = 0; c < 7; c++) {
                __half h = __float2half_rn(e[c] * inv);
                w[c] = (short)__half_as_ushort(h);
            }
            tv = tg[y * WW + x];
        }
        *(short8*)(&sp[p * 8]) = w;
        st[p] = (unsigned char)tv;
    }
    __syncthreads();

    // ---- Phase B ----
    float accF = 0.f, accB = 0.f;
    float sumP[7] = {0,0,0,0,0,0,0};
    float inter[7] = {0,0,0,0,0,0,0};
    float cnt[7] = {0,0,0,0,0,0,0};
    float num[5] = {0,0,0,0,0};
    const int gy_base = blockIdx.y * 32;
    const int gx_base = blockIdx.x * 32;
    const unsigned char* rm_img = rmask + (size_t)b * HW;

#pragma unroll
    for (int k = 0; k < 4; k++) {
        int p = tid + k * 256;
        int cy = p >> 5, cx = p & 31;
        int hp = (cy + 1) * 34 + (cx + 1);
        int t = st[hp];
        short8 v = *(const short8*)(&sp[hp * 8]);
        float pr[7];
#pragma unroll
        for (int c = 0; c < 7; c++) pr[c] = __half2float(__ushort_as_half((unsigned short)v[c]));

        // focal
        float p_t = __half2float(__ushort_as_half(sp[hp * 8 + t]));  // dynamic idx stays in LDS
        float wt = sw[t];
        float nll = -__logf(p_t);
        float ce = wt * nll;
        float ptv = __expf(-ce);
        float om = 1.0f - ptv;
        accF += om * om * ce;

        // boundary weights: one precomputed byte
        unsigned rm = rm_img[(gy_base + cy) * WW + (gx_base + cx)];

#pragma unroll
        for (int c = 0; c < 7; c++) {
            float prc = pr[c];
            sumP[c] += prc;
            bool is = (c == t);
            if (is) { inter[c] += prc; cnt[c] += 1.0f; }
            float bw = 1.0f + 4.0f * (float)((rm >> c) & 1u);
            float bce = is ? -__logf(prc + 1e-7f) : -__logf(1.0f - prc + 1e-7f);
            accB += bw * bce;
        }

        // topo: dynamic-channel 9-neighbor gather (stays in LDS), static scatter to num[]
        if (t >= 2) {
            float s = 0.f;
#pragma unroll
            for (int dy = -1; dy <= 1; dy++) {
#pragma unroll
                for (int dx = -1; dx <= 1; dx++) {
                    int np = hp + dy * 34 + dx;
                    float pn = __half2float(__ushort_as_half(sp[np * 8 + t]));
                    s += pn - ((st[np] == t) ? 1.0f : 0.0f);
                }
            }
            float val = fabsf(s) * (1.0f / 9.0f);
#pragma unroll
            for (int j = 0; j < 5; j++) num[j] += (t == j + 2) ? val : 0.f;
        }
    }

    // ---- Phase C: block reduce + atomics + last-block finalize ----
    float vals[28];
    vals[0] = accF; vals[1] = accB;
#pragma unroll
    for (int c = 0; c < 7; c++) { vals[2+c] = sumP[c]; vals[9+c] = inter[c]; vals[16+c] = cnt[c]; }
#pragma unroll
    for (int j = 0; j < 5; j++) vals[23+j] = num[j];

    int lane = tid & 63, wid = tid >> 6;
#pragma unroll
    for (int i = 0; i < 28; i++) {
        float v = vals[i];
#pragma unroll
        for (int o = 32; o > 0; o >>= 1) v += __shfl_down(v, o, 64);
        if (lane == 0) sred[wid * 28 + i] = v;
    }
    __syncthreads();
    if (tid < 28) {
        float s = sred[tid] + sred[28 + tid] + sred[56 + tid] + sred[84 + tid];
        atomicAdd(&acc[tid], (double)s);
    }
    __threadfence();
    __syncthreads();
    if (tid == 0) {
        unsigned t = atomicAdd(ticket, 1u);
        if (t == NBLK - 1) {
            // atomic reads -> device-coherent view of acc
            double focal = atomicAdd(&acc[0], 0.0) / (double)((size_t)BB * HW);
            double bound = atomicAdd(&acc[1], 0.0) / (double)((size_t)BB * CC * HW);
            double dice = 0.0;
#pragma unroll
            for (int c = 0; c < 7; c++) {
                double sP = atomicAdd(&acc[2 + c], 0.0);
                double in2 = atomicAdd(&acc[9 + c], 0.0);
                double cn = atomicAdd(&acc[16 + c], 0.0);
                dice += 1.0 - (2.0 * in2 + 1e-6) / (sP + cn + 1e-6);
            }
            dice *= (1.0 / 7.0);
            double topo = 0.0;
#pragma unroll
            for (int j = 0; j < 5; j++) {
                double ms = atomicAdd(&acc[18 + j], 0.0);
                double nm = atomicAdd(&acc[23 + j], 0.0);
                topo += (ms >= 1.0) ? nm / fmax(ms, 1.0) : 0.0;
            }
            topo *= (1.0 / 5.0);
            out[0] = (float)(0.3 * focal + 0.3 * dice + 0.2 * bound + 0.2 * topo);
        }
    }
}

extern "C" void kernel_launch(void* const* d_in, const int* in_sizes, int n_in,
                              void* d_out, int out_size, void* d_ws, size_t ws_size,
                              hipStream_t stream) {
    const float* logits = (const float*)d_in[0];
    const int* tgt = (const int*)d_in[1];
    const float* cw = (const float*)d_in[2];
    float* out = (float*)d_out;

    char* ws = (char*)d_ws;
    double* acc = (double*)ws;
    unsigned* ticket = (unsigned*)(ws + 224);
    unsigned char* hmask = (unsigned char*)(ws + 256);
    unsigned char* rmask = hmask + (size_t)BB * HW;

    hipMemsetAsync(ws, 0, 256, stream);

    bmaskh_kernel<<<BB * HH, 256, 0, stream>>>(tgt, hmask);
    vor_kernel<<<(BB * HW / 4 + 255) / 256, 256, 0, stream>>>(hmask, rmask);

    dim3 grid(WW / 32, HH / 32, BB);
    main_kernel<<<grid, 256, 0, stream>>>(logits, tgt, cw, rmask, acc, ticket, out);
}

// Round 3
// 265.265 us; speedup vs baseline: 1.0726x; 1.0726x over previous
//
#include <hip/hip_runtime.h>
#include <hip/hip_fp16.h>

#define BB 8
#define CC 7
#define HH 512
#define WW 512
#define HW (HH*WW)
#define NBLK (16*16*8)

// ws layout:
//   [0,224)    28 doubles: [0]=focal [1]=bce [2..8]=sumP [9..15]=inter [16..22]=cnt [23..27]=topo_num
//   [224,228)  uint ticket counter

// Single fused kernel. One block = 32x32 output pixels of one image.
//  step1: 38x38 target tile (±3 halo) -> LDS (255 = OOB sentinel)
//  step2: boundary bits bm[36][36] (±2): |lap(onehot_c)|>0, zero-padded
//  step3: horizontal 5-OR -> hm[36][32]
//  step4: softmax over 34x34 (±1) halo; interior pixels accumulate
//         focal/dice/bce in f32 registers; probs ch2..6 -> 5 planar f16 planes
//  step5: topo 3x3 gather from planes (channel = center target)
//  step6: block reduce -> 28 double atomics -> last-block finalize
__global__ __launch_bounds__(256) void main_kernel(const float* __restrict__ logits,
                                                   const int* __restrict__ tgt,
                                                   const float* __restrict__ cw,
                                                   double* __restrict__ acc,
                                                   unsigned* __restrict__ ticket,
                                                   float* __restrict__ out) {
    __shared__ unsigned char st[38 * 38 + 4];   // targets ±3
    __shared__ unsigned char bm[36 * 36 + 4];   // boundary bits ±2
    __shared__ unsigned char hm[36 * 32];       // horizontal 5-OR
    __shared__ unsigned short sp[5 * 1164];     // f16 probs, planar, ch 2..6, 34x34 halo
    __shared__ float sw[8];
    __shared__ float sred[4 * 28];

    const int tid = threadIdx.x;
    const int b = blockIdx.z;
    const int gx0 = blockIdx.x * 32;
    const int gy0 = blockIdx.y * 32;
    if (tid < 7) sw[tid] = cw[tid];

    const float* lg = logits + (size_t)b * CC * HW;
    const int* tg = tgt + (size_t)b * HW;

    // ---- step 1: targets ±3 ----
    for (int p = tid; p < 1444; p += 256) {
        int iy = p / 38, ix = p - iy * 38;
        int y = gy0 - 3 + iy, x = gx0 - 3 + ix;
        int tv = 255;
        if ((unsigned)y < HH && (unsigned)x < WW) tv = tg[y * WW + x];
        st[p] = (unsigned char)tv;
    }
    __syncthreads();

    // ---- step 2: boundary bits (zero-pad laplacian semantics) ----
    for (int p = tid; p < 1296; p += 256) {
        int by = p / 36, bx = p - by * 36;
        int y = gy0 - 2 + by, x = gx0 - 2 + bx;
        unsigned bits = 0;
        if ((unsigned)y < HH && (unsigned)x < WW) {
            int si = (by + 1) * 38 + (bx + 1);
            int t = st[si];
            unsigned orm = 0; int nfirst = -1, same = 1, ninb = 0;
            int n;
            n = st[si - 38]; if (n != 255) { orm |= 1u << n; if (nfirst < 0) nfirst = n; else same &= (n == nfirst); ninb++; }
            n = st[si + 38]; if (n != 255) { orm |= 1u << n; if (nfirst < 0) nfirst = n; else same &= (n == nfirst); ninb++; }
            n = st[si - 1];  if (n != 255) { orm |= 1u << n; if (nfirst < 0) nfirst = n; else same &= (n == nfirst); ninb++; }
            n = st[si + 1];  if (n != 255) { orm |= 1u << n; if (nfirst < 0) nfirst = n; else same &= (n == nfirst); ninb++; }
            unsigned andm = (ninb == 4 && same) ? (1u << nfirst) : 0u;
            unsigned cbit = 1u << t;
            bits = (orm & ~cbit) | (cbit & ~andm);
        }
        bm[p] = (unsigned char)bits;
    }
    __syncthreads();

    // ---- step 3: horizontal 5-OR ----
    for (int p = tid; p < 1152; p += 256) {
        int hy = p >> 5, hx = p & 31;
        const unsigned char* r = &bm[hy * 36 + hx];
        hm[p] = (unsigned char)(r[0] | r[1] | r[2] | r[3] | r[4]);
    }
    __syncthreads();

    // ---- step 4: softmax halo + per-pixel f32 terms ----
    float accF = 0.f, accB = 0.f;
    float sumP[7] = {0,0,0,0,0,0,0};
    float inter[7] = {0,0,0,0,0,0,0};
    float cnt[7] = {0,0,0,0,0,0,0};
    float num[5] = {0,0,0,0,0};

    for (int p = tid; p < 1156; p += 256) {
        int iy = p / 34, ix = p - iy * 34;
        int y = gy0 - 1 + iy, x = gx0 - 1 + ix;
        float pr[7] = {0,0,0,0,0,0,0};
        if ((unsigned)y < HH && (unsigned)x < WW) {
            const float* lp = lg + y * WW + x;
            float l[7], e[7];
            float se = 0.f;
#pragma unroll
            for (int c = 0; c < 7; c++) { l[c] = lp[c * HW]; }
#pragma unroll
            for (int c = 0; c < 7; c++) { e[c] = __expf(l[c]); se += e[c]; }
            float inv = 1.0f / se;
#pragma unroll
            for (int c = 0; c < 7; c++) pr[c] = e[c] * inv;

            if ((unsigned)(iy - 1) < 32u && (unsigned)(ix - 1) < 32u) {
                int t = st[(iy + 2) * 38 + (ix + 2)];
                // focal: nll = log(se) - l_t  (exact log-softmax)
                float lt = l[0];
#pragma unroll
                for (int c = 1; c < 7; c++) lt = (t == c) ? l[c] : lt;
                float nll = __logf(se) - lt;
                float ce = sw[t] * nll;
                float ptv = __expf(-ce);
                float om = 1.0f - ptv;
                accF += om * om * ce;

                // dice partials
#pragma unroll
                for (int c = 0; c < 7; c++) {
                    float m = (t == c) ? 1.0f : 0.0f;
                    sumP[c] += pr[c];
                    cnt[c] += m;
                    inter[c] += m * pr[c];
                }

                // boundary-weighted bce; region bit = vertical 5-OR of hm
                int cy = iy - 1, cx = ix - 1;
                const unsigned char* hc = &hm[cy * 32 + cx];
                unsigned rm = (unsigned)(hc[0] | hc[32] | hc[64] | hc[96] | hc[128]);
#pragma unroll
                for (int c = 0; c < 7; c++) {
                    float q = 1.0f - pr[c] + 1e-7f;
                    float arg = (t == c) ? (pr[c] + 1e-7f) : q;
                    float bw = 1.0f + 4.0f * (float)((rm >> c) & 1u);
                    accB -= bw * __logf(arg);
                }
            }
        }
        // planar f16 planes for topo (zeros when OOB)
#pragma unroll
        for (int j = 0; j < 5; j++)
            sp[j * 1164 + p] = __half_as_ushort(__float2half_rn(pr[j + 2]));
    }
    __syncthreads();

    // ---- step 5: topo ----
#pragma unroll
    for (int k = 0; k < 4; k++) {
        int p = tid + k * 256;
        int cy = p >> 5, cx = p & 31;
        int t = st[(cy + 3) * 38 + (cx + 3)];
        if ((unsigned)(t - 2) < 5u) {
            int pl = (t - 2) * 1164;
            int hp = (cy + 1) * 34 + (cx + 1);
            float s = 0.f;
#pragma unroll
            for (int dy = -1; dy <= 1; dy++) {
#pragma unroll
                for (int dx = -1; dx <= 1; dx++) {
                    int np = hp + dy * 34 + dx;
                    float pn = __half2float(__ushort_as_half(sp[pl + np]));
                    int sn = st[(cy + 3 + dy) * 38 + (cx + 3 + dx)];
                    s += pn - ((sn == t) ? 1.0f : 0.0f);
                }
            }
            float val = fabsf(s) * (1.0f / 9.0f);
#pragma unroll
            for (int j = 0; j < 5; j++) num[j] += (t == j + 2) ? val : 0.f;
        }
    }

    // ---- step 6: reduce + atomics + last-block finalize ----
    float vals[28];
    vals[0] = accF; vals[1] = accB;
#pragma unroll
    for (int c = 0; c < 7; c++) { vals[2+c] = sumP[c]; vals[9+c] = inter[c]; vals[16+c] = cnt[c]; }
#pragma unroll
    for (int j = 0; j < 5; j++) vals[23+j] = num[j];

    int lane = tid & 63, wid = tid >> 6;
#pragma unroll
    for (int i = 0; i < 28; i++) {
        float v = vals[i];
#pragma unroll
        for (int o = 32; o > 0; o >>= 1) v += __shfl_down(v, o, 64);
        if (lane == 0) sred[wid * 28 + i] = v;
    }
    __syncthreads();
    if (tid < 28) {
        float s = sred[tid] + sred[28 + tid] + sred[56 + tid] + sred[84 + tid];
        atomicAdd(&acc[tid], (double)s);
    }
    __threadfence();
    __syncthreads();
    if (tid == 0) {
        unsigned t = atomicAdd(ticket, 1u);
        if (t == NBLK - 1) {
            __threadfence();
            double focal = atomicAdd(&acc[0], 0.0) / (double)((size_t)BB * HW);
            double bound = atomicAdd(&acc[1], 0.0) / (double)((size_t)BB * CC * HW);
            double dice = 0.0;
#pragma unroll
            for (int c = 0; c < 7; c++) {
                double sP = atomicAdd(&acc[2 + c], 0.0);
                double in2 = atomicAdd(&acc[9 + c], 0.0);
                double cn = atomicAdd(&acc[16 + c], 0.0);
                dice += 1.0 - (2.0 * in2 + 1e-6) / (sP + cn + 1e-6);
            }
            dice *= (1.0 / 7.0);
            double topo = 0.0;
#pragma unroll
            for (int j = 0; j < 5; j++) {
                double ms = atomicAdd(&acc[18 + j], 0.0);
                double nm = atomicAdd(&acc[23 + j], 0.0);
                topo += (ms >= 1.0) ? nm / fmax(ms, 1.0) : 0.0;
            }
            topo *= (1.0 / 5.0);
            out[0] = (float)(0.3 * focal + 0.3 * dice + 0.2 * bound + 0.2 * topo);
        }
    }
}

extern "C" void kernel_launch(void* const* d_in, const int* in_sizes, int n_in,
                              void* d_out, int out_size, void* d_ws, size_t ws_size,
                              hipStream_t stream) {
    const float* logits = (const float*)d_in[0];
    const int* tgt = (const int*)d_in[1];
    const float* cw = (const float*)d_in[2];
    float* out = (float*)d_out;

    char* ws = (char*)d_ws;
    double* acc = (double*)ws;
    unsigned* ticket = (unsigned*)(ws + 224);

    hipMemsetAsync(ws, 0, 256, stream);

    dim3 grid(WW / 32, HH / 32, BB);
    main_kernel<<<grid, 256, 0, stream>>>(logits, tgt, cw, acc, ticket, out);
}

// Round 4
// 164.686 us; speedup vs baseline: 1.7276x; 1.6107x over previous
//
#include <hip/hip_runtime.h>

#define BB 8
#define CC 7
#define HH 512
#define WW 512
#define HW (HH*WW)

// ws layout:
//   [0,224)  28 doubles: [0]=focal [1]=bce [2..8]=sumP [9..15]=inter [16..22]=cnt [23..27]=topo_num

// Fused main kernel (R1's proven-fast phase structure + in-LDS mask computation).
// One block = 32x32 output pixels of one image.
//  step1: 38x38 target tile (±3) -> LDS (255 = OOB)
//  step2: boundary bits bm[36][36] (±2) = |lap(onehot)|>0, zero-padded
//  step3: horizontal 5-OR -> hm[36][32]
//  phaseA: softmax for 34x34 (±1) halo -> f32 LDS, stride 7 (28B, conflict-free)
//  phaseB: uniform 4x256 interior pixels: focal/dice/bce (+vertical 5-OR) /topo
//  phaseC: wave reduce -> 28 plain double atomics. NO threadfence/ticket
//          (R2/R3 showed per-block device fence doubles runtime).
__global__ __launch_bounds__(256) void main_kernel(const float* __restrict__ logits,
                                                   const int* __restrict__ tgt,
                                                   const float* __restrict__ cw,
                                                   double* __restrict__ acc) {
    __shared__ float sp[1156 * 7];              // f32 probs, halo tile
    __shared__ unsigned char st[38 * 38 + 2];   // targets ±3
    __shared__ unsigned char bm[36 * 36 + 4];   // boundary bits ±2
    __shared__ unsigned char hm[36 * 32];       // horizontal 5-OR
    __shared__ float sw[8];
    __shared__ float sred[4 * 28];

    const int tid = threadIdx.x;
    const int b = blockIdx.z;
    const int gx0 = blockIdx.x * 32;
    const int gy0 = blockIdx.y * 32;
    if (tid < 7) sw[tid] = cw[tid];

    const float* lg = logits + (size_t)b * CC * HW;
    const int* tg = tgt + (size_t)b * HW;

    // ---- step 1: targets ±3 ----
    for (int p = tid; p < 1444; p += 256) {
        int iy = p / 38, ix = p - iy * 38;
        int y = gy0 - 3 + iy, x = gx0 - 3 + ix;
        int tv = 255;
        if ((unsigned)y < HH && (unsigned)x < WW) tv = tg[y * WW + x];
        st[p] = (unsigned char)tv;
    }
    __syncthreads();

    // ---- step 2: boundary bits ----
    for (int p = tid; p < 1296; p += 256) {
        int by = p / 36, bx = p - by * 36;
        int y = gy0 - 2 + by, x = gx0 - 2 + bx;
        unsigned bits = 0;
        if ((unsigned)y < HH && (unsigned)x < WW) {
            int si = (by + 1) * 38 + (bx + 1);
            int t = st[si];
            unsigned orm = 0; int nfirst = -1, same = 1, ninb = 0;
            int n;
            n = st[si - 38]; if (n != 255) { orm |= 1u << n; if (nfirst < 0) nfirst = n; else same &= (n == nfirst); ninb++; }
            n = st[si + 38]; if (n != 255) { orm |= 1u << n; if (nfirst < 0) nfirst = n; else same &= (n == nfirst); ninb++; }
            n = st[si - 1];  if (n != 255) { orm |= 1u << n; if (nfirst < 0) nfirst = n; else same &= (n == nfirst); ninb++; }
            n = st[si + 1];  if (n != 255) { orm |= 1u << n; if (nfirst < 0) nfirst = n; else same &= (n == nfirst); ninb++; }
            unsigned andm = (ninb == 4 && same) ? (1u << nfirst) : 0u;
            unsigned cbit = 1u << t;
            bits = (orm & ~cbit) | (cbit & ~andm);
        }
        bm[p] = (unsigned char)bits;
    }
    __syncthreads();

    // ---- step 3: horizontal 5-OR ----
    for (int p = tid; p < 1152; p += 256) {
        int hy = p >> 5, hx = p & 31;
        const unsigned char* r = &bm[hy * 36 + hx];
        hm[p] = (unsigned char)(r[0] | r[1] | r[2] | r[3] | r[4]);
    }
    __syncthreads();

    // ---- phase A: softmax halo -> f32 LDS ----
    for (int p = tid; p < 1156; p += 256) {
        int iy = p / 34, ix = p - iy * 34;
        int y = gy0 - 1 + iy, x = gx0 - 1 + ix;
        float pr[7] = {0,0,0,0,0,0,0};
        if ((unsigned)y < HH && (unsigned)x < WW) {
            const float* lp = lg + y * WW + x;
            float e[7]; float se = 0.f;
#pragma unroll
            for (int c = 0; c < 7; c++) { e[c] = __expf(lp[c * HW]); se += e[c]; }
            float inv = 1.0f / se;
#pragma unroll
            for (int c = 0; c < 7; c++) pr[c] = e[c] * inv;
        }
#pragma unroll
        for (int c = 0; c < 7; c++) sp[p * 7 + c] = pr[c];
    }
    __syncthreads();

    // ---- phase B: uniform interior sweep ----
    float accF = 0.f, accB = 0.f;
    float sumP[7] = {0,0,0,0,0,0,0};
    float inter[7] = {0,0,0,0,0,0,0};
    float cnt[7] = {0,0,0,0,0,0,0};
    float num[5] = {0,0,0,0,0};

#pragma unroll
    for (int k = 0; k < 4; k++) {
        int p = tid + k * 256;
        int cy = p >> 5, cx = p & 31;
        int hp = (cy + 1) * 34 + (cx + 1);
        int t = st[(cy + 3) * 38 + (cx + 3)];
        float pr[7];
#pragma unroll
        for (int c = 0; c < 7; c++) pr[c] = sp[hp * 7 + c];

        // focal
        float p_t = sp[hp * 7 + t];            // dynamic LDS index
        float ce = sw[t] * (-__logf(p_t));
        float ptv = __expf(-ce);
        float om = 1.0f - ptv;
        accF += om * om * ce;

        // region bit: vertical 5-OR of hm
        const unsigned char* hc = &hm[cy * 32 + cx];
        unsigned rm = (unsigned)(hc[0] | hc[32] | hc[64] | hc[96] | hc[128]);

#pragma unroll
        for (int c = 0; c < 7; c++) {
            float prc = pr[c];
            bool is = (c == t);
            sumP[c] += prc;
            if (is) { inter[c] += prc; cnt[c] += 1.0f; }
            float arg = is ? (prc + 1e-7f) : (1.0f - prc + 1e-7f);
            float bw = 1.0f + 4.0f * (float)((rm >> c) & 1u);
            accB -= bw * __logf(arg);
        }

        // topo: dynamic-channel 3x3 gather
        if ((unsigned)(t - 2) < 5u) {
            float s = 0.f;
#pragma unroll
            for (int dy = -1; dy <= 1; dy++) {
#pragma unroll
                for (int dx = -1; dx <= 1; dx++) {
                    int np = hp + dy * 34 + dx;
                    float pn = sp[np * 7 + t];
                    int sn = st[(cy + 3 + dy) * 38 + (cx + 3 + dx)];
                    s += pn - ((sn == t) ? 1.0f : 0.0f);
                }
            }
            float val = fabsf(s) * (1.0f / 9.0f);
#pragma unroll
            for (int j = 0; j < 5; j++) num[j] += (t == j + 2) ? val : 0.f;
        }
    }

    // ---- phase C: reduce + plain atomics ----
    float vals[28];
    vals[0] = accF; vals[1] = accB;
#pragma unroll
    for (int c = 0; c < 7; c++) { vals[2+c] = sumP[c]; vals[9+c] = inter[c]; vals[16+c] = cnt[c]; }
#pragma unroll
    for (int j = 0; j < 5; j++) vals[23+j] = num[j];

    int lane = tid & 63, wid = tid >> 6;
#pragma unroll
    for (int i = 0; i < 28; i++) {
        float v = vals[i];
#pragma unroll
        for (int o = 32; o > 0; o >>= 1) v += __shfl_down(v, o, 64);
        if (lane == 0) sred[wid * 28 + i] = v;
    }
    __syncthreads();
    if (tid < 28) {
        float s = sred[tid] + sred[28 + tid] + sred[56 + tid] + sred[84 + tid];
        atomicAdd(&acc[tid], (double)s);
    }
}

// ---------------------------------------------------------------------------
__global__ void finalize_kernel(const double* __restrict__ acc, float* __restrict__ out) {
    if (threadIdx.x == 0 && blockIdx.x == 0) {
        double focal = acc[0] / (double)((size_t)BB * HW);
        double bound = acc[1] / (double)((size_t)BB * CC * HW);
        double dice = 0.0;
#pragma unroll
        for (int c = 0; c < 7; c++) {
            double uni = acc[2 + c] + acc[16 + c];
            dice += 1.0 - (2.0 * acc[9 + c] + 1e-6) / (uni + 1e-6);
        }
        dice *= (1.0 / 7.0);
        double topo = 0.0;
#pragma unroll
        for (int j = 0; j < 5; j++) {
            double ms = acc[18 + j];
            double nm = acc[23 + j];
            topo += (ms >= 1.0) ? nm / fmax(ms, 1.0) : 0.0;
        }
        topo *= (1.0 / 5.0);
        out[0] = (float)(0.3 * focal + 0.3 * dice + 0.2 * bound + 0.2 * topo);
    }
}

extern "C" void kernel_launch(void* const* d_in, const int* in_sizes, int n_in,
                              void* d_out, int out_size, void* d_ws, size_t ws_size,
                              hipStream_t stream) {
    const float* logits = (const float*)d_in[0];
    const int* tgt = (const int*)d_in[1];
    const float* cw = (const float*)d_in[2];
    float* out = (float*)d_out;

    double* acc = (double*)d_ws;
    hipMemsetAsync(d_ws, 0, 256, stream);

    dim3 grid(WW / 32, HH / 32, BB);
    main_kernel<<<grid, 256, 0, stream>>>(logits, tgt, cw, acc);
    finalize_kernel<<<1, 64, 0, stream>>>(acc, out);
}